// Round 4
// baseline (1006.860 us; speedup 1.0000x reference)
//
#include <hip/hip_runtime.h>

// ---------------- problem constants ----------------
constexpr int N   = 8192;   // nodes
constexpr int F0  = 512;    // nfeat
constexpr int H1  = 128;    // nhid
constexpr int NH  = 2;      // heads
constexpr int C2  = 64;     // nclass
constexpr int CP  = 16;     // cluster_pre
constexpr int NS1 = 4;      // j-slices, layer-1 attention
constexpr int NS2 = 8;      // j-slices, layer-2 attention

typedef __attribute__((ext_vector_type(8))) short  short8;
typedef __attribute__((ext_vector_type(4))) float  float4v;

#define DEVI __device__ __forceinline__

DEVI float bf2f(unsigned short u) { return __uint_as_float(((unsigned int)u) << 16); }
DEVI unsigned short f2bf(float f) {
  unsigned int u = __float_as_uint(f);
  return (unsigned short)((u + 0x7fffu + ((u >> 16) & 1u)) >> 16);   // RNE
}
DEVI float elu1(float x) { return x > 0.f ? x : __expf(x) - 1.f; }
DEVI float lrelu_exp(float e) {                      // exp(leaky_relu(e)), overflow-guarded
  e = fmaxf(e, 0.2f * e);                            // alpha = 0.2
  return __expf(fminf(e, 60.f));
}
DEVI float4v mfma16(short8 a, short8 b, float4v c) {
  return __builtin_amdgcn_mfma_f32_16x16x32_bf16(a, b, c, 0, 0, 0);
}

// ---------------- inline dtype sniff (per wave; no cross-kernel state) --------
// Reads W1's first 1024 halfwords (2048 B = full buffer if bf16, half if f32).
// bf16 xavier W1: all |v|<=0.39 -> cnt=0 -> flag=1. f32: low halfwords are
// random mantissa bits -> ~half decode |bf16|>1 or NaN -> cnt~256 -> flag=0.
DEVI int sniff_wave(const unsigned short* __restrict__ w1) {
  const int lane = threadIdx.x & 63;
  int cnt = 0;
#pragma unroll
  for (int t = 0; t < 16; t++) {
    const float v = bf2f(w1[lane * 16 + t]);
    if (!(fabsf(v) <= 1.0f)) cnt++;                  // catches NaN too
  }
  for (int off = 32; off; off >>= 1) cnt += __shfl_down(cnt, off);
  cnt = __shfl(cnt, 0);
  return (cnt > 64) ? 0 : 1;                         // 1=bf16, 0=f32
}

// ---------------- 0) convert any float input -> bf16 scratch ----------------
__global__ __launch_bounds__(256) void k_convert(const void* __restrict__ src,
                                                 unsigned short* __restrict__ dst,
                                                 const unsigned short* __restrict__ w1,
                                                 int n4) {
  const int flag = sniff_wave(w1);
  const int t = blockIdx.x * 256 + threadIdx.x;
  if (t >= n4) return;
  if (flag) {                                    // already bf16: passthrough 4 elems
    ((uint2*)dst)[t] = ((const uint2*)src)[t];
  } else {                                       // f32 -> bf16
    const float4 v = ((const float4*)src)[t];
    ushort4 o;
    o.x = f2bf(v.x); o.y = f2bf(v.y); o.z = f2bf(v.z); o.w = f2bf(v.w);
    ((ushort4*)dst)[t] = o;
  }
}

// ---------------- 1) adj -> bitmask ----------------
__global__ __launch_bounds__(256) void k_pack_mask(const int* __restrict__ adj,
                                                   unsigned long long* __restrict__ mb) {
  const long long g = (long long)blockIdx.x * 256 + threadIdx.x;
  const unsigned long long bits = __ballot(adj[g] > 0);
  if ((threadIdx.x & 63) == 0) mb[g >> 6] = bits;
}

// ---------------- 2) pack weight W[K][COLS] -> Wp[(k/8)][col][8] ----------------
template <int COLS>
__global__ __launch_bounds__(256) void k_pack_w(const unsigned short* __restrict__ W,
                                                unsigned short* __restrict__ Wp, int K) {
  const int t = blockIdx.x * 256 + threadIdx.x;
  if (t >= K * COLS) return;
  const int k = t / COLS, n = t % COLS;
  Wp[((size_t)(k >> 3) * COLS + n) * 8 + (k & 7)] = W[t];
}

// ---------------- 3) GEMM C = A @ W (packed); outputs f32 + packed bf16 ----------------
template <int KDIM, int COLS>
__global__ __launch_bounds__(256) void k_gemm(const unsigned short* __restrict__ A,
                                              const unsigned short* __restrict__ Wp,
                                              float* __restrict__ Cf,
                                              unsigned short* __restrict__ Cp) {
  constexpr int NT = COLS / 16;
  const int lane = threadIdx.x & 63, w = threadIdx.x >> 6;
  const int quad = lane >> 4, r16 = lane & 15;
  const int rb = blockIdx.x * 64 + w * 16;
  float4v acc[NT];
#pragma unroll
  for (int nt = 0; nt < NT; nt++) acc[nt] = (float4v){0.f, 0.f, 0.f, 0.f};
  const short* As = (const short*)A;
  const short* Ws = (const short*)Wp;
  for (int kc = 0; kc < KDIM; kc += 32) {
    const short8 af = *(const short8*)(As + (size_t)(rb + r16) * KDIM + kc + quad * 8);
#pragma unroll
    for (int nt = 0; nt < NT; nt++) {
      const short8 bf = *(const short8*)(Ws + ((size_t)((kc >> 3) + quad) * COLS + nt * 16 + r16) * 8);
      acc[nt] = mfma16(af, bf, acc[nt]);
    }
  }
  const int row0 = rb + quad * 4;                  // C/D: row=quad*4+reg, col=lane&15
#pragma unroll
  for (int nt = 0; nt < NT; nt++) {
    const int col = nt * 16 + r16;
    unsigned long long pk = 0;
#pragma unroll
    for (int r = 0; r < 4; r++) {
      Cf[(size_t)(row0 + r) * COLS + col] = acc[nt][r];
      pk |= (unsigned long long)f2bf(acc[nt][r]) << (16 * r);
    }
    *(unsigned long long*)(Cp + ((size_t)(row0 >> 3) * COLS + col) * 8 + (row0 & 7)) = pk;
  }
}

// ---------------- 4) f1/f2 = Wh @ a halves ----------------
template <int COLS>
__global__ __launch_bounds__(256) void k_f1f2(const float* __restrict__ Wh,
                                              const unsigned short* __restrict__ a,
                                              float* __restrict__ f1, float* __restrict__ f2) {
  const int lane = threadIdx.x & 63, w = threadIdx.x >> 6;
  const int row = blockIdx.x * 4 + w;
  const float* r = Wh + (size_t)row * COLS;
  float s1 = 0.f, s2 = 0.f;
#pragma unroll
  for (int k = lane; k < COLS; k += 64) {
    const float v = r[k];
    s1 += v * bf2f(a[k]);
    s2 += v * bf2f(a[COLS + k]);
  }
  for (int off = 32; off; off >>= 1) { s1 += __shfl_down(s1, off); s2 += __shfl_down(s2, off); }
  if (lane == 0) { f1[row] = s1; f2[row] = s2; }
}

// ---------------- 5) softmax denominators ----------------
__global__ __launch_bounds__(256) void k_denom(const unsigned long long* __restrict__ mb,
                                               const float* __restrict__ f1,
                                               const float* __restrict__ f2,
                                               float* __restrict__ den) {
  __shared__ float f2s[N];
  for (int t = threadIdx.x; t < N; t += 256) f2s[t] = f2[t];
  __syncthreads();
  const int lane = threadIdx.x & 63, w = threadIdx.x >> 6;
  for (int rr = 0; rr < 8; rr++) {
    const int row = blockIdx.x * 32 + w * 8 + rr;
    const float f1r = f1[row];
    const unsigned long long* mrow = mb + (size_t)row * (N / 64);
    float acc = 0.f;
    for (int t = 0; t < N / 64; t++) {
      const unsigned long long m = mrow[t];
      float p = lrelu_exp(f1r + f2s[t * 64 + lane]);
      if (!((m >> lane) & 1ull)) p = 0.f;
      acc += p;
    }
    for (int off = 32; off; off >>= 1) acc += __shfl_down(acc, off);
    if (lane == 0) den[row] = acc;
  }
}

// ---------------- 6) attention numerator: part = P_slice @ Wh (MFMA) ----------------
template <int COLS>
__global__ __launch_bounds__(256) void k_attn(const unsigned char* __restrict__ mbytes,
                                              const float* __restrict__ f1_all,
                                              const float* __restrict__ f2_all,
                                              const unsigned short* __restrict__ Whp_all,
                                              float* __restrict__ part_all, int jspan) {
  constexpr int NT = COLS / 16;
  const int lane = threadIdx.x & 63, w = threadIdx.x >> 6;
  const int quad = lane >> 4, r16 = lane & 15;
  const int head = blockIdx.y;
  const int rb = blockIdx.x * 128 + w * 32;
  const float* f1 = f1_all + (size_t)head * N;
  const float* f2 = f2_all + (size_t)head * N;
  const short* Wp = (const short*)(Whp_all + (size_t)head * N * COLS);
  float* part = part_all + (size_t)(blockIdx.z * gridDim.y + head) * N * COLS;
  const float f1r0 = f1[rb + r16];
  const float f1r1 = f1[rb + 16 + r16];
  const unsigned char* mrow0 = mbytes + (size_t)(rb + r16) * (N / 8);
  const unsigned char* mrow1 = mbytes + (size_t)(rb + 16 + r16) * (N / 8);
  float4v acc[2][NT];
#pragma unroll
  for (int mt = 0; mt < 2; mt++)
#pragma unroll
    for (int nt = 0; nt < NT; nt++) acc[mt][nt] = (float4v){0.f, 0.f, 0.f, 0.f};

  const int j0 = blockIdx.z * jspan;
  for (int jc = j0; jc < j0 + jspan; jc += 32) {
    const int jq = jc + quad * 8;
    const float4v fA = *(const float4v*)(f2 + jq);
    const float4v fB = *(const float4v*)(f2 + jq + 4);
    const unsigned int m0 = mrow0[jq >> 3];
    const unsigned int m1 = mrow1[jq >> 3];
    short8 af0, af1;
#pragma unroll
    for (int jj = 0; jj < 8; jj++) {
      const float fj = (jj < 4) ? fA[jj] : fB[jj - 4];
      float p0 = lrelu_exp(f1r0 + fj); if (!((m0 >> jj) & 1u)) p0 = 0.f;
      float p1 = lrelu_exp(f1r1 + fj); if (!((m1 >> jj) & 1u)) p1 = 0.f;
      af0[jj] = (short)f2bf(p0);
      af1[jj] = (short)f2bf(p1);
    }
#pragma unroll
    for (int nt = 0; nt < NT; nt++) {
      const short8 bf = *(const short8*)(Wp + ((size_t)(jq >> 3) * COLS + nt * 16 + r16) * 8);
      acc[0][nt] = mfma16(af0, bf, acc[0][nt]);
      acc[1][nt] = mfma16(af1, bf, acc[1][nt]);
    }
  }
#pragma unroll
  for (int mt = 0; mt < 2; mt++) {
    const int row0 = rb + mt * 16 + quad * 4;
#pragma unroll
    for (int nt = 0; nt < NT; nt++) {
      const int col = nt * 16 + r16;
#pragma unroll
      for (int r = 0; r < 4; r++) part[(size_t)(row0 + r) * COLS + col] = acc[mt][nt][r];
    }
  }
}

// ---------------- 7) combine slices ----------------
__global__ __launch_bounds__(256) void k_combine1(const float* __restrict__ part,
                                                  const float* __restrict__ den,
                                                  unsigned short* __restrict__ h) {
  const int t = blockIdx.x * 256 + threadIdx.x;
  const int i = t >> 8, col = t & 255;
  const int head = col >> 7, c = col & 127;
  float s = 0.f;
#pragma unroll
  for (int sl = 0; sl < NS1; sl++) s += part[((size_t)(sl * NH + head) * N + i) * H1 + c];
  const float v = s / den[(size_t)head * N + i];
  h[t] = f2bf(elu1(v));
}

// combine2: write mu straight to its OUTPUT slot (dtype-branched)
__global__ __launch_bounds__(256) void k_combine2(const float* __restrict__ part,
                                                  const float* __restrict__ den,
                                                  const unsigned short* __restrict__ w1,
                                                  void* __restrict__ outbase) {
  const int flag = sniff_wave(w1);
  const int t = blockIdx.x * 256 + threadIdx.x;   // N*C2
  const int i = t >> 6;
  float s = 0.f;
#pragma unroll
  for (int sl = 0; sl < NS2; sl++) s += part[((size_t)sl * N + i) * C2 + (t & 63)];
  const float v = elu1(s / den[i]);
  const size_t NN = (size_t)N * N;
  if (flag) ((unsigned short*)outbase)[NN + t] = f2bf(v);
  else      ((float*)outbase)[NN + t] = v;
}

// ---------------- 8) class_pre = softmax(mu @ W1); mu from OUTPUT slot --------
// MUST run BEFORE k_recon (reads W1B scratch inside the recon region).
__global__ __launch_bounds__(256) void k_classpre(const unsigned short* __restrict__ W1B,
                                                  const unsigned short* __restrict__ w1raw,
                                                  void* __restrict__ outbase) {
  const int flag = sniff_wave(w1raw);
  __shared__ float w1s[C2 * CP];
  for (int t = threadIdx.x; t < C2 * CP; t += 256) w1s[t] = bf2f(W1B[t]);
  __syncthreads();
  const float* muf = (const float*)((const char*)outbase + (size_t)N * N * 4);
  const unsigned short* mub = (const unsigned short*)((const char*)outbase + (size_t)N * N * 2);
  const int i = blockIdx.x * 256 + threadIdx.x;
  float logit[CP];
#pragma unroll
  for (int c = 0; c < CP; c++) logit[c] = 0.f;
  for (int k = 0; k < C2; k++) {
    const float m = flag ? bf2f(mub[(size_t)i * C2 + k]) : muf[(size_t)i * C2 + k];
#pragma unroll
    for (int c = 0; c < CP; c++) logit[c] += m * w1s[k * CP + c];
  }
  float mx = logit[0];
#pragma unroll
  for (int c = 1; c < CP; c++) mx = fmaxf(mx, logit[c]);
  float se = 0.f;
#pragma unroll
  for (int c = 0; c < CP; c++) { logit[c] = __expf(logit[c] - mx); se += logit[c]; }
  const float inv = 1.f / se;
  const size_t off = (size_t)N * N + (size_t)N * C2;
  if (flag) {
    unsigned short* o = (unsigned short*)outbase + off + (size_t)i * CP;
#pragma unroll
    for (int c = 0; c < CP; c++) o[c] = f2bf(logit[c] * inv);
  } else {
    float* o = (float*)outbase + off + (size_t)i * CP;
#pragma unroll
    for (int c = 0; c < CP; c++) o[c] = logit[c] * inv;
  }
}

// ---------------- 9) reconstruction = mu @ mu.T ----------------
// Reads mu ONLY from its output slot (outside the recon region it writes) ->
// no read/write race. f32 world: in-register hi/lo bf16 split (exact to 2^-17);
// bf16 world: hi only.
__global__ __launch_bounds__(256) void k_recon(const unsigned short* __restrict__ w1raw,
                                               void* __restrict__ outbase) {
  const int flag = sniff_wave(w1raw);
  const int lane = threadIdx.x & 63, w = threadIdx.x >> 6;
  const int quad = lane >> 4, r16 = lane & 15;
  const int rb = blockIdx.x * 64 + w * 16;
  const int cb = blockIdx.y * 128;
  const float* muf = (const float*)((const char*)outbase + (size_t)N * N * 4);
  const short* mub = (const short*)((const char*)outbase + (size_t)N * N * 2);

  auto load_frag = [&](int row, int kc, short8& hi, short8& lo) {
    if (flag) {
      hi = *(const short8*)(mub + (size_t)row * C2 + kc + quad * 8);
      lo = (short8){0, 0, 0, 0, 0, 0, 0, 0};
    } else {
      const float4 a = *(const float4*)(muf + (size_t)row * C2 + kc + quad * 8);
      const float4 b = *(const float4*)(muf + (size_t)row * C2 + kc + quad * 8 + 4);
      float vv[8] = {a.x, a.y, a.z, a.w, b.x, b.y, b.z, b.w};
#pragma unroll
      for (int j = 0; j < 8; j++) {
        const unsigned short h = f2bf(vv[j]);
        hi[j] = (short)h;
        lo[j] = (short)f2bf(vv[j] - bf2f(h));
      }
    }
  };

  float4v acc[8];
#pragma unroll
  for (int nt = 0; nt < 8; nt++) acc[nt] = (float4v){0.f, 0.f, 0.f, 0.f};
#pragma unroll
  for (int kc = 0; kc < C2; kc += 32) {
    short8 ah_, al_;
    load_frag(rb + r16, kc, ah_, al_);
#pragma unroll
    for (int nt = 0; nt < 8; nt++) {
      short8 bh, bl;
      load_frag(cb + nt * 16 + r16, kc, bh, bl);
      acc[nt] = mfma16(ah_, bh, acc[nt]);
      if (!flag) {
        acc[nt] = mfma16(ah_, bl, acc[nt]);
        acc[nt] = mfma16(al_, bh, acc[nt]);
      }
    }
  }
  const int row0 = rb + quad * 4;
#pragma unroll
  for (int nt = 0; nt < 8; nt++) {
    const int col = cb + nt * 16 + r16;
#pragma unroll
    for (int r = 0; r < 4; r++) {
      if (flag) ((unsigned short*)outbase)[(size_t)(row0 + r) * N + col] = f2bf(acc[nt][r]);
      else      ((float*)outbase)[(size_t)(row0 + r) * N + col] = acc[nt][r];
    }
  }
}

// ---------------- launcher ----------------
// All scratch lives in d_out's recon region ([0, 128 MiB), valid for either
// out dtype). k_recon is launched LAST and reads nothing from that region.
extern "C" void kernel_launch(void* const* d_in, const int* in_sizes, int n_in,
                              void* d_out, int out_size, void* d_ws, size_t ws_size,
                              hipStream_t stream) {
  (void)in_sizes; (void)n_in; (void)out_size; (void)d_ws; (void)ws_size;
  const void* x   = d_in[0];                       // [N][F0]
  const int*  adj = (const int*)d_in[1];           // [N][N] i32
  const void* Whd = d_in[2];                       // [NH][F0][H1]
  const void* ah  = d_in[3];                       // [NH][2*H1]
  const void* Wo  = d_in[4];                       // [2*H1][C2]
  const void* ao  = d_in[5];                       // [2*C2]
  const unsigned short* W1 = (const unsigned short*)d_in[6];   // [C2][CP]

  char* ob = (char*)d_out;
  size_t off = 0;
  auto take = [&](size_t b) -> char* { char* p = ob + off; off += (b + 255) & ~(size_t)255; return p; };
  unsigned long long* MB = (unsigned long long*)take((size_t)N * N / 8);        //  8 MiB
  float*          PART1 = (float*)take((size_t)NS1 * NH * N * H1 * 4);          // 32 MiB
  float*          PART2 = (float*)take((size_t)NS2 * N * C2 * 4);               // 16 MiB
  float*          WhF   = (float*)take((size_t)NH * N * H1 * 4);                //  8 MiB
  unsigned short* Whp   = (unsigned short*)take((size_t)NH * N * H1 * 2);       //  4 MiB
  unsigned short* HBF   = (unsigned short*)take((size_t)N * 2 * H1 * 2);        //  4 MiB
  unsigned short* XB    = (unsigned short*)take((size_t)N * F0 * 2);            //  8 MiB
  float*          Wh2F  = (float*)take((size_t)N * C2 * 4);                     //  2 MiB
  unsigned short* Wh2P  = (unsigned short*)take((size_t)N * C2 * 2);            //  1 MiB
  unsigned short* WhdB  = (unsigned short*)take((size_t)NH * F0 * H1 * 2);
  unsigned short* WP1   = (unsigned short*)take((size_t)NH * F0 * H1 * 2);
  unsigned short* WoB   = (unsigned short*)take((size_t)2 * H1 * C2 * 2);
  unsigned short* WP2   = (unsigned short*)take((size_t)2 * H1 * C2 * 2);
  unsigned short* ahB   = (unsigned short*)take((size_t)NH * 2 * H1 * 2);
  unsigned short* aoB   = (unsigned short*)take((size_t)2 * C2 * 2);
  unsigned short* W1B   = (unsigned short*)take((size_t)C2 * CP * 2);
  float*          F1    = (float*)take((size_t)NH * N * 4);
  float*          F2    = (float*)take((size_t)NH * N * 4);
  float*          DEN1  = (float*)take((size_t)NH * N * 4);
  float*          F1B   = (float*)take((size_t)N * 4);
  float*          F2B   = (float*)take((size_t)N * 4);
  float*          DEN2  = (float*)take((size_t)N * 4);
  // total ~84 MiB < 128 MiB recon region (either out dtype)

  const dim3 B(256);
  k_convert<<<dim3((N * F0 / 4 + 255) / 256), B, 0, stream>>>(x, XB, W1, N * F0 / 4);
  k_convert<<<dim3((NH * F0 * H1 / 4 + 255) / 256), B, 0, stream>>>(Whd, WhdB, W1, NH * F0 * H1 / 4);
  k_convert<<<dim3(1), B, 0, stream>>>(ah, ahB, W1, NH * 2 * H1 / 4);
  k_convert<<<dim3((2 * H1 * C2 / 4 + 255) / 256), B, 0, stream>>>(Wo, WoB, W1, 2 * H1 * C2 / 4);
  k_convert<<<dim3(1), B, 0, stream>>>(ao, aoB, W1, 2 * C2 / 4);
  k_convert<<<dim3(1), B, 0, stream>>>(W1, W1B, W1, C2 * CP / 4);

  k_pack_mask<<<dim3((unsigned)((size_t)N * N / 256)), B, 0, stream>>>(adj, MB);
  k_pack_w<H1><<<dim3((F0 * H1) / 256), B, 0, stream>>>(WhdB, WP1, F0);
  k_pack_w<H1><<<dim3((F0 * H1) / 256), B, 0, stream>>>(WhdB + F0 * H1, WP1 + F0 * H1, F0);
  k_pack_w<C2><<<dim3((2 * H1 * C2) / 256), B, 0, stream>>>(WoB, WP2, 2 * H1);

  for (int h = 0; h < NH; h++) {
    k_gemm<F0, H1><<<dim3(N / 64), B, 0, stream>>>(XB, WP1 + (size_t)h * F0 * H1,
                                                   WhF + (size_t)h * N * H1, Whp + (size_t)h * N * H1);
    k_f1f2<H1><<<dim3(N / 4), B, 0, stream>>>(WhF + (size_t)h * N * H1, ahB + (size_t)h * 2 * H1,
                                              F1 + (size_t)h * N, F2 + (size_t)h * N);
    k_denom<<<dim3(N / 32), B, 0, stream>>>(MB, F1 + (size_t)h * N, F2 + (size_t)h * N, DEN1 + (size_t)h * N);
  }
  k_attn<H1><<<dim3(N / 128, NH, NS1), B, 0, stream>>>((const unsigned char*)MB, F1, F2, Whp, PART1, N / NS1);
  k_combine1<<<dim3((N * 2 * H1) / 256), B, 0, stream>>>(PART1, DEN1, HBF);

  k_gemm<2 * H1, C2><<<dim3(N / 64), B, 0, stream>>>(HBF, WP2, Wh2F, Wh2P);
  k_f1f2<C2><<<dim3(N / 4), B, 0, stream>>>(Wh2F, aoB, F1B, F2B);
  k_denom<<<dim3(N / 32), B, 0, stream>>>(MB, F1B, F2B, DEN2);
  k_attn<C2><<<dim3(N / 128, 1, NS2), B, 0, stream>>>((const unsigned char*)MB, F1B, F2B, Wh2P, PART2, N / NS2);
  k_combine2<<<dim3((N * C2) / 256), B, 0, stream>>>(PART2, DEN2, W1, d_out);

  k_classpre<<<dim3(N / 256), B, 0, stream>>>(W1B, W1, d_out);   // before k_recon!
  k_recon<<<dim3(N / 64, N / 128), B, 0, stream>>>(W1, d_out);
}